// Round 1
// baseline (229.089 us; speedup 1.0000x reference)
//
#include <hip/hip_runtime.h>
#include <hip/hip_bf16.h>

#define Bv 4
#define Tv 2048
#define Ev 1024
#define Hv 16
#define Sv 64

typedef __attribute__((ext_vector_type(8))) short bf16x8;
typedef __attribute__((ext_vector_type(4))) short bf16x4;
typedef __attribute__((ext_vector_type(4))) float f32x4;

// 16x16x16 bf16 MFMA (A/B = 4 bf16 = 2 VGPR) — builtin name varies by ROCm
#if __has_builtin(__builtin_amdgcn_mfma_f32_16x16x16_bf16)
#define MFMA161616(a, b, c) __builtin_amdgcn_mfma_f32_16x16x16_bf16(a, b, c, 0, 0, 0)
#elif __has_builtin(__builtin_amdgcn_mfma_f32_16x16x16bf16_1k)
#define MFMA161616(a, b, c) __builtin_amdgcn_mfma_f32_16x16x16bf16_1k(a, b, c, 0, 0, 0)
#else
__device__ __forceinline__ f32x4 mfma161616_asm(bf16x4 a, bf16x4 b, f32x4 c) {
    f32x4 d;
    asm("v_mfma_f32_16x16x16_bf16 %0, %1, %2, %3" : "=v"(d) : "v"(a), "v"(b), "v"(c));
    return d;
}
#define MFMA161616(a, b, c) mfma161616_asm(a, b, c)
#endif

__device__ __forceinline__ ushort f2bf(float f) {
    unsigned u = __float_as_uint(f);
    u = (u + 0x7FFFu + ((u >> 16) & 1u)) >> 16;
    return (ushort)u;
}
// RNE pack via v_cvt_pk_bf16_f32 (header lowers to HW instr on gfx950)
__device__ __forceinline__ unsigned pkrn(float a, float b) {
    __hip_bfloat162 t = __float22bfloat162_rn(make_float2(a, b));
    unsigned r; __builtin_memcpy(&r, &t, 4); return r;
}
// truncation pack, 1 VALU op (v_perm_b32): {lo=a_trunc, hi=b_trunc}
__device__ __forceinline__ unsigned pktr(float a, float b) {
    return __builtin_amdgcn_perm(__float_as_uint(b), __float_as_uint(a), 0x07060302u);
}

// async global->LDS, 16B per lane (global_load_lds_dwordx4)
__device__ __forceinline__ void async16(void* lds, const void* g) {
    __builtin_amdgcn_global_load_lds(
        (const __attribute__((address_space(1))) unsigned int*)g,
        (__attribute__((address_space(3))) unsigned int*)lds, 16, 0, 0);
}

// ---------------------------------------------------------------------------
// Kernel 0: cast weights fp32 -> bf16. Blocks 0..1023: Wp. 1024..1026: Wq/Wk/Wv
// Wq folded with (1/32)*log2(e): attn uses exp2 so v_exp_f32 needs no mul.
// ---------------------------------------------------------------------------
__global__ __launch_bounds__(256) void cast_kernel(
    const float* __restrict__ Wp, const float* __restrict__ Wq,
    const float* __restrict__ Wk, const float* __restrict__ Wv,
    ushort* __restrict__ Wpb, ushort* __restrict__ Wqb,
    ushort* __restrict__ Wkb, ushort* __restrict__ Wvb)
{
    int blk = blockIdx.x;
    if (blk < 1024) {
        int i = (blk * 256 + threadIdx.x) * 4;
        float4 v = *(const float4*)(Wp + i);
        uint2 o = {pkrn(v.x, v.y), pkrn(v.z, v.w)};
        *(uint2*)(Wpb + i) = o;
    } else {
        int p = blk - 1024;
        const float* src = (p == 0) ? Wq : ((p == 1) ? Wk : Wv);
        ushort* dst      = (p == 0) ? Wqb : ((p == 1) ? Wkb : Wvb);
        const float scale = (p == 0) ? 0.03125f * 1.4426950408889634f : 1.0f;
        #pragma unroll
        for (int it = 0; it < 4; ++it) {
            int i = (it * 256 + threadIdx.x) * 4;
            float4 v = *(const float4*)(src + i);
            uint2 o = {pkrn(v.x * scale, v.y * scale), pkrn(v.z * scale, v.w * scale)};
            *(uint2*)(dst + i) = o;
        }
    }
}

// ---------------------------------------------------------------------------
// Kernel 1: QKV projection via MFMA, no LDS. (unchanged this round)
// ---------------------------------------------------------------------------
__global__ __launch_bounds__(192) void qkv_kernel(
    const float* __restrict__ x,
    const ushort* __restrict__ Wqb, const ushort* __restrict__ Wkb,
    const ushort* __restrict__ Wvb,
    ushort* __restrict__ Q, ushort* __restrict__ K, ushort* __restrict__ Vt)
{
    const int tid  = threadIdx.x;
    const int wave = tid >> 6;        // 0=Q 1=K 2=V
    const int lane = tid & 63;
    const int m    = lane & 15;
    const int quad = lane >> 4;

    const ushort* Wsel = (wave == 0) ? Wqb : ((wave == 1) ? Wkb : Wvb);
    bf16x8 wf[4][2];
    #pragma unroll
    for (int ot = 0; ot < 4; ++ot)
        #pragma unroll
        for (int ks = 0; ks < 2; ++ks)
            wf[ot][ks] = *(const bf16x8*)&Wsel[(ot * 16 + m) * 64 + ks * 32 + quad * 8];

    const int tt = blockIdx.x >> 2;   // 0..511 token tile
    const int hg = blockIdx.x & 3;    // head group
    const int g0 = tt * 16;
    const int gm = g0 + m;
    const int b  = g0 >> 11;
    const int t0 = g0 & 2047;

    #pragma unroll
    for (int hi = 0; hi < 4; ++hi) {
        const int h  = hg * 4 + hi;
        const int bh = b * Hv + h;

        bf16x8 xf[2];
        #pragma unroll
        for (int ks = 0; ks < 2; ++ks) {
            const float* src = x + (size_t)gm * Ev + h * Sv + ks * 32 + quad * 8;
            float4 v0 = *(const float4*)src;
            float4 v1 = *(const float4*)(src + 4);
            unsigned pk[4];
            pk[0] = pkrn(v0.x, v0.y); pk[1] = pkrn(v0.z, v0.w);
            pk[2] = pkrn(v1.x, v1.y); pk[3] = pkrn(v1.z, v1.w);
            xf[ks] = *(bf16x8*)pk;
        }

        f32x4 acc[4];
        #pragma unroll
        for (int ot = 0; ot < 4; ++ot) acc[ot] = (f32x4){0.f, 0.f, 0.f, 0.f};

        if (wave < 2) {
            #pragma unroll
            for (int ks = 0; ks < 2; ++ks)
                #pragma unroll
                for (int ot = 0; ot < 4; ++ot)
                    acc[ot] = __builtin_amdgcn_mfma_f32_16x16x32_bf16(
                        wf[ot][ks], xf[ks], acc[ot], 0, 0, 0);
            ushort* dst = ((wave == 0) ? Q : K)
                        + ((size_t)bh * Tv + t0 + m) * Sv + quad * 4;
            #pragma unroll
            for (int ot = 0; ot < 4; ++ot) {
                uint2 w = {pkrn(acc[ot][0], acc[ot][1]), pkrn(acc[ot][2], acc[ot][3])};
                *(uint2*)(dst + ot * 16) = w;
            }
        } else {
            #pragma unroll
            for (int ks = 0; ks < 2; ++ks)
                #pragma unroll
                for (int st = 0; st < 4; ++st)
                    acc[st] = __builtin_amdgcn_mfma_f32_16x16x32_bf16(
                        xf[ks], wf[st][ks], acc[st], 0, 0, 0);
            ushort* vr = Vt + ((size_t)bh * Sv + m) * Tv + t0 + quad * 4;
            #pragma unroll
            for (int st = 0; st < 4; ++st) {
                uint2 w = {pkrn(acc[st][0], acc[st][1]), pkrn(acc[st][2], acc[st][3])};
                *(uint2*)(vr + (size_t)st * 16 * Tv) = w;
            }
        }
    }
}

// ---------------------------------------------------------------------------
// Kernel 2: flash attention v8 — v7 + DOUBLE-BUFFERED 2-PHASE PIPELINE.
// v7's loop was {sync; issue global_load_lds; sync(vmcnt0 drain); compute}:
// every wave ate the full L2 load latency with nothing in the shadow
// (MfmaUtil 50 + VALUBusy 47 = serialized pipes). Now: one barrier/iter,
// prefetch tile t+1 into buf^1 right after the barrier, compute tile t —
// the vmcnt(0) drain at the NEXT barrier is covered by ~400cy of compute.
// LDS 33KB -> still 4 blocks/CU (grid-capped at 4 anyway).
// ---------------------------------------------------------------------------
__global__ __launch_bounds__(256, 4) void attn_kernel(
    const ushort* __restrict__ Q, const ushort* __restrict__ K,
    const ushort* __restrict__ Vt, ushort* __restrict__ O)
{
    __shared__ ushort kl[2][64 * 64];     // K tile  [key][d]   (swizzled)
    __shared__ ushort vl[2][64 * 64];     // Vt tile [s][key]   (swizzled)
    __shared__ float  ll[4][32];          // per-wave 1/lsum bounce

    const int tid  = threadIdx.x;
    const int wave = tid >> 6;
    const int lane = tid & 63;
    const int m    = lane & 15;
    const int quad = lane >> 4;
    const int bh   = blockIdx.x & 63;
    const int q0   = (blockIdx.x >> 6) << 7;   // query tile base (128)

    // Q fragments (B-operand of S^T = K·Q^T)
    const ushort* Qb = Q + ((size_t)bh * Tv + q0 + wave * 32) * Sv;
    bf16x8 qf[2][2];
    #pragma unroll
    for (int g = 0; g < 2; ++g)
        #pragma unroll
        for (int ks = 0; ks < 2; ++ks)
            qf[g][ks] = *(const bf16x8*)&Qb[(g * 16 + m) * Sv + ks * 32 + quad * 8];

    f32x4 oa[2][4];
    float lsum[2] = {0.f, 0.f};
    #pragma unroll
    for (int g = 0; g < 2; ++g)
        #pragma unroll
        for (int st = 0; st < 4; ++st)
            oa[g][st] = (f32x4){0.f, 0.f, 0.f, 0.f};

    const ushort* Kb = K  + (size_t)bh * Tv * Sv;
    const ushort* Vb = Vt + (size_t)bh * Sv * Tv;

    // staging geometry (swizzled): chunk c -> row=c>>3, phys cg=c&7,
    // source col-group = (c&7) ^ (row&7)
    const int r0 = tid >> 3,         cg0 = (tid & 7) ^ (r0 & 7);
    const int r1 = (256 + tid) >> 3, cg1 = ((256 + tid) & 7) ^ (r1 & 7);
    const size_t koff0 = (size_t)r0 * Sv + cg0 * 8;
    const size_t koff1 = (size_t)r1 * Sv + cg1 * 8;
    const size_t voff0 = (size_t)r0 * Tv + cg0 * 8;
    const size_t voff1 = (size_t)r1 * Tv + cg1 * 8;
    const int mx = m & 7;

    // prologue: stage tile 0 into buffer 0
    async16(&kl[0][(size_t)tid * 8],         Kb + koff0);
    async16(&kl[0][((size_t)tid + 256) * 8], Kb + koff1);
    async16(&vl[0][(size_t)tid * 8],         Vb + voff0);
    async16(&vl[0][((size_t)tid + 256) * 8], Vb + voff1);

    for (int t = 0; t < Tv / 64; ++t) {
        const int cur = t & 1;
        // waits vmcnt(0): tile t's loads landed; all waves done reading buf^1
        __syncthreads();

        // prefetch tile t+1 into the other buffer — in flight during compute
        if (t + 1 < Tv / 64) {
            const int nxt = cur ^ 1;
            const size_t k0n = (size_t)(t + 1) * 64;
            async16(&kl[nxt][(size_t)tid * 8],         Kb + k0n * Sv + koff0);
            async16(&kl[nxt][((size_t)tid + 256) * 8], Kb + k0n * Sv + koff1);
            async16(&vl[nxt][(size_t)tid * 8],         Vb + k0n + voff0);
            async16(&vl[nxt][((size_t)tid + 256) * 8], Vb + k0n + voff1);
        }

        // S^T = K·Q^T -> exp2 -> P packed into registers (A-frag layout
        // of 16x16x16: lane (m,quad) = P[q=g*16+m][key=nt*16+quad*4+j])
        bf16x4 w[4][2];
        #pragma unroll
        for (int nt = 0; nt < 4; ++nt) {
            const int krow = nt * 16 + m;
            bf16x8 a0 = *(const bf16x8*)&kl[cur][krow * 64 + ((quad       ^ mx) * 8)];
            bf16x8 a1 = *(const bf16x8*)&kl[cur][krow * 64 + (((4 + quad) ^ mx) * 8)];
            #pragma unroll
            for (int g = 0; g < 2; ++g) {
                f32x4 s = (f32x4){0.f, 0.f, 0.f, 0.f};
                s = __builtin_amdgcn_mfma_f32_16x16x32_bf16(a0, qf[g][0], s, 0, 0, 0);
                s = __builtin_amdgcn_mfma_f32_16x16x32_bf16(a1, qf[g][1], s, 0, 0, 0);
                float p0 = __builtin_amdgcn_exp2f(s[0]);
                float p1 = __builtin_amdgcn_exp2f(s[1]);
                float p2 = __builtin_amdgcn_exp2f(s[2]);
                float p3 = __builtin_amdgcn_exp2f(s[3]);
                lsum[g] += (p0 + p1) + (p2 + p3);
                unsigned pk[2] = {pktr(p0, p1), pktr(p2, p3)};
                w[nt][g] = *(bf16x4*)pk;
            }
        }

        // PV via 16x16x16: A = w (registers), B = Vt b64 frags from vl.
        // B-frag (st,kt): Vt_tile[s=st*16+m][keys kt*16+quad*4 ..+3]
        #pragma unroll
        for (int st = 0; st < 4; ++st) {
            const int srow = st * 16 + m;
            bf16x4 vf[4];
            #pragma unroll
            for (int kt = 0; kt < 4; ++kt)
                vf[kt] = *(const bf16x4*)&vl[cur][srow * 64
                           + (((2 * kt + (quad >> 1)) ^ mx) * 8) + (quad & 1) * 4];
            #pragma unroll
            for (int g = 0; g < 2; ++g)
                #pragma unroll
                for (int kt = 0; kt < 4; ++kt)
                    oa[g][st] = MFMA161616(w[kt][g], vf[kt], oa[g][st]);
        }
    }

    // lsum: reduce across quads; redistribute 1/l via wave-private LDS
    #pragma unroll
    for (int g = 0; g < 2; ++g) {
        lsum[g] += __shfl_xor(lsum[g], 16, 64);
        lsum[g] += __shfl_xor(lsum[g], 32, 64);
    }
    if (lane < 16) {
        ll[wave][lane]      = 1.0f / lsum[0];
        ll[wave][16 + lane] = 1.0f / lsum[1];
    }

    const int b = bh >> 4, h = bh & 15;
    #pragma unroll
    for (int g = 0; g < 2; ++g)
        #pragma unroll
        for (int st = 0; st < 4; ++st)
            #pragma unroll
            for (int r = 0; r < 4; ++r)
                O[((size_t)(b * Tv + q0 + wave * 32 + g * 16 + quad * 4 + r)) * Ev
                  + h * Sv + st * 16 + m]
                    = f2bf(oa[g][st][r] * ll[wave][g * 16 + quad * 4 + r]);
}

// ---------------------------------------------------------------------------
// Kernel 3: output projection, bf16 MFMA — same 2-phase double-buffer
// conversion (512 blocks = only 2/CU: nothing hides the vmcnt(0) drain,
// so prefetch-next ∥ compute-current matters even more here).
// ---------------------------------------------------------------------------
__global__ __launch_bounds__(256) void proj_kernel(
    const ushort* __restrict__ A, const ushort* __restrict__ B,
    const float* __restrict__ bp, float* __restrict__ C)
{
    __shared__ ushort Asm[2][128 * 32];
    __shared__ ushort Bsm[2][128 * 32];
    const int tid  = threadIdx.x;
    const int wave = tid >> 6;
    const int lane = tid & 63;
    const int m    = lane & 15;
    const int quad = lane >> 4;
    const int wm   = wave >> 1;
    const int wn   = wave & 1;
    const int m0   = blockIdx.x * 128;
    const int n0   = blockIdx.y * 128;

    f32x4 acc[4][4];
    #pragma unroll
    for (int i = 0; i < 4; ++i)
        #pragma unroll
        for (int j = 0; j < 4; ++j)
            acc[i][j] = (f32x4){0.f, 0.f, 0.f, 0.f};

    const int row_ = tid >> 2, col_ = (tid & 3) * 8;
    const int rowh = (256 + tid) >> 2, colh = ((256 + tid) & 3) * 8;

    // prologue: stage k0=0 into buffer 0
    async16(&Asm[0][(size_t)tid * 8],         &A[(size_t)(m0 + row_) * Ev + col_]);
    async16(&Asm[0][((size_t)tid + 256) * 8], &A[(size_t)(m0 + rowh) * Ev + colh]);
    async16(&Bsm[0][(size_t)tid * 8],         &B[(size_t)(n0 + row_) * Ev + col_]);
    async16(&Bsm[0][((size_t)tid + 256) * 8], &B[(size_t)(n0 + rowh) * Ev + colh]);

    for (int t = 0; t < Ev / 32; ++t) {
        const int cur = t & 1;
        __syncthreads();   // tile t loads landed; buf^1 free

        if (t + 1 < Ev / 32) {
            const int nxt = cur ^ 1;
            const int k0n = (t + 1) * 32;
            async16(&Asm[nxt][(size_t)tid * 8],         &A[(size_t)(m0 + row_) * Ev + k0n + col_]);
            async16(&Asm[nxt][((size_t)tid + 256) * 8], &A[(size_t)(m0 + rowh) * Ev + k0n + colh]);
            async16(&Bsm[nxt][(size_t)tid * 8],         &B[(size_t)(n0 + row_) * Ev + k0n + col_]);
            async16(&Bsm[nxt][((size_t)tid + 256) * 8], &B[(size_t)(n0 + rowh) * Ev + k0n + colh]);
        }

        bf16x8 af[4], bf[4];
        #pragma unroll
        for (int i = 0; i < 4; ++i)
            af[i] = *(const bf16x8*)&Asm[cur][(wm * 64 + i * 16 + m) * 32 + quad * 8];
        #pragma unroll
        for (int j = 0; j < 4; ++j)
            bf[j] = *(const bf16x8*)&Bsm[cur][(wn * 64 + j * 16 + m) * 32 + quad * 8];
        #pragma unroll
        for (int i = 0; i < 4; ++i)
            #pragma unroll
            for (int j = 0; j < 4; ++j)
                acc[i][j] = __builtin_amdgcn_mfma_f32_16x16x32_bf16(
                    af[i], bf[j], acc[i][j], 0, 0, 0);
    }

    float bbv[4];
    #pragma unroll
    for (int j = 0; j < 4; ++j)
        bbv[j] = bp[n0 + wn * 64 + j * 16 + m];

    #pragma unroll
    for (int i = 0; i < 4; ++i)
        #pragma unroll
        for (int j = 0; j < 4; ++j)
            #pragma unroll
            for (int r = 0; r < 4; ++r)
                C[(size_t)(m0 + wm * 64 + i * 16 + quad * 4 + r) * Ev
                  + n0 + wn * 64 + j * 16 + m] = acc[i][j][r] + bbv[j];
}

// ---------------------------------------------------------------------------
// ws layout (ushort units):
//   Q 8.4M | K 8.4M | Vt 8.4M | O 8.4M | Wpb 1M | Wqb 4096 | Wkb 4096 | Wvb 4096
// ---------------------------------------------------------------------------
extern "C" void kernel_launch(void* const* d_in, const int* in_sizes, int n_in,
                              void* d_out, int out_size, void* d_ws, size_t ws_size,
                              hipStream_t stream) {
    const float* x  = (const float*)d_in[0];
    const float* Wk = (const float*)d_in[1];
    const float* Wq = (const float*)d_in[2];
    const float* Wv = (const float*)d_in[3];
    const float* Wp = (const float*)d_in[4];
    const float* bp = (const float*)d_in[5];
    float* out = (float*)d_out;

    ushort* Q   = (ushort*)d_ws;
    ushort* K   = Q   + 8388608;
    ushort* Vt  = K   + 8388608;
    ushort* O   = Vt  + 8388608;
    ushort* Wpb = O   + 8388608;
    ushort* Wqb = Wpb + 1048576;
    ushort* Wkb = Wqb + 4096;
    ushort* Wvb = Wkb + 4096;

    cast_kernel<<<1027, 256, 0, stream>>>(Wp, Wq, Wk, Wv, Wpb, Wqb, Wkb, Wvb);
    qkv_kernel<<<2048, 192, 0, stream>>>(x, Wqb, Wkb, Wvb, Q, K, Vt);
    attn_kernel<<<1024, 256, 0, stream>>>(Q, K, Vt, O);
    proj_kernel<<<dim3(64, 8), 256, 0, stream>>>(O, Wpb, bp, out);
}

// Round 2
// 224.973 us; speedup vs baseline: 1.0183x; 1.0183x over previous
//
#include <hip/hip_runtime.h>
#include <hip/hip_bf16.h>

#define Bv 4
#define Tv 2048
#define Ev 1024
#define Hv 16
#define Sv 64

typedef __attribute__((ext_vector_type(8))) short bf16x8;
typedef __attribute__((ext_vector_type(4))) short bf16x4;
typedef __attribute__((ext_vector_type(4))) float f32x4;

// 16x16x16 bf16 MFMA (A/B = 4 bf16 = 2 VGPR) — builtin name varies by ROCm
#if __has_builtin(__builtin_amdgcn_mfma_f32_16x16x16_bf16)
#define MFMA161616(a, b, c) __builtin_amdgcn_mfma_f32_16x16x16_bf16(a, b, c, 0, 0, 0)
#elif __has_builtin(__builtin_amdgcn_mfma_f32_16x16x16bf16_1k)
#define MFMA161616(a, b, c) __builtin_amdgcn_mfma_f32_16x16x16bf16_1k(a, b, c, 0, 0, 0)
#else
__device__ __forceinline__ f32x4 mfma161616_asm(bf16x4 a, bf16x4 b, f32x4 c) {
    f32x4 d;
    asm("v_mfma_f32_16x16x16_bf16 %0, %1, %2, %3" : "=v"(d) : "v"(a), "v"(b), "v"(c));
    return d;
}
#define MFMA161616(a, b, c) mfma161616_asm(a, b, c)
#endif

__device__ __forceinline__ ushort f2bf(float f) {
    unsigned u = __float_as_uint(f);
    u = (u + 0x7FFFu + ((u >> 16) & 1u)) >> 16;
    return (ushort)u;
}
// RNE pack via v_cvt_pk_bf16_f32 (header lowers to HW instr on gfx950)
__device__ __forceinline__ unsigned pkrn(float a, float b) {
    __hip_bfloat162 t = __float22bfloat162_rn(make_float2(a, b));
    unsigned r; __builtin_memcpy(&r, &t, 4); return r;
}
// truncation pack, 1 VALU op (v_perm_b32): {lo=a_trunc, hi=b_trunc}
__device__ __forceinline__ unsigned pktr(float a, float b) {
    return __builtin_amdgcn_perm(__float_as_uint(b), __float_as_uint(a), 0x07060302u);
}

// async global->LDS, 16B per lane (global_load_lds_dwordx4)
__device__ __forceinline__ void async16(void* lds, const void* g) {
    __builtin_amdgcn_global_load_lds(
        (const __attribute__((address_space(1))) unsigned int*)g,
        (__attribute__((address_space(3))) unsigned int*)lds, 16, 0, 0);
}

// ---------------------------------------------------------------------------
// Kernel 0: cast weights fp32 -> bf16. Blocks 0..1023: Wp. 1024..1026: Wq/Wk/Wv
// Wq folded with (1/32)*log2(e): attn uses exp2 so v_exp_f32 needs no mul.
// ---------------------------------------------------------------------------
__global__ __launch_bounds__(256) void cast_kernel(
    const float* __restrict__ Wp, const float* __restrict__ Wq,
    const float* __restrict__ Wk, const float* __restrict__ Wv,
    ushort* __restrict__ Wpb, ushort* __restrict__ Wqb,
    ushort* __restrict__ Wkb, ushort* __restrict__ Wvb)
{
    int blk = blockIdx.x;
    if (blk < 1024) {
        int i = (blk * 256 + threadIdx.x) * 4;
        float4 v = *(const float4*)(Wp + i);
        uint2 o = {pkrn(v.x, v.y), pkrn(v.z, v.w)};
        *(uint2*)(Wpb + i) = o;
    } else {
        int p = blk - 1024;
        const float* src = (p == 0) ? Wq : ((p == 1) ? Wk : Wv);
        ushort* dst      = (p == 0) ? Wqb : ((p == 1) ? Wkb : Wvb);
        const float scale = (p == 0) ? 0.03125f * 1.4426950408889634f : 1.0f;
        #pragma unroll
        for (int it = 0; it < 4; ++it) {
            int i = (it * 256 + threadIdx.x) * 4;
            float4 v = *(const float4*)(src + i);
            uint2 o = {pkrn(v.x * scale, v.y * scale), pkrn(v.z * scale, v.w * scale)};
            *(uint2*)(dst + i) = o;
        }
    }
}

// ---------------------------------------------------------------------------
// Kernel 1: QKV projection via MFMA, no LDS. (unchanged)
// ---------------------------------------------------------------------------
__global__ __launch_bounds__(192) void qkv_kernel(
    const float* __restrict__ x,
    const ushort* __restrict__ Wqb, const ushort* __restrict__ Wkb,
    const ushort* __restrict__ Wvb,
    ushort* __restrict__ Q, ushort* __restrict__ K, ushort* __restrict__ Vt)
{
    const int tid  = threadIdx.x;
    const int wave = tid >> 6;        // 0=Q 1=K 2=V
    const int lane = tid & 63;
    const int m    = lane & 15;
    const int quad = lane >> 4;

    const ushort* Wsel = (wave == 0) ? Wqb : ((wave == 1) ? Wkb : Wvb);
    bf16x8 wf[4][2];
    #pragma unroll
    for (int ot = 0; ot < 4; ++ot)
        #pragma unroll
        for (int ks = 0; ks < 2; ++ks)
            wf[ot][ks] = *(const bf16x8*)&Wsel[(ot * 16 + m) * 64 + ks * 32 + quad * 8];

    const int tt = blockIdx.x >> 2;   // 0..511 token tile
    const int hg = blockIdx.x & 3;    // head group
    const int g0 = tt * 16;
    const int gm = g0 + m;
    const int b  = g0 >> 11;
    const int t0 = g0 & 2047;

    #pragma unroll
    for (int hi = 0; hi < 4; ++hi) {
        const int h  = hg * 4 + hi;
        const int bh = b * Hv + h;

        bf16x8 xf[2];
        #pragma unroll
        for (int ks = 0; ks < 2; ++ks) {
            const float* src = x + (size_t)gm * Ev + h * Sv + ks * 32 + quad * 8;
            float4 v0 = *(const float4*)src;
            float4 v1 = *(const float4*)(src + 4);
            unsigned pk[4];
            pk[0] = pkrn(v0.x, v0.y); pk[1] = pkrn(v0.z, v0.w);
            pk[2] = pkrn(v1.x, v1.y); pk[3] = pkrn(v1.z, v1.w);
            xf[ks] = *(bf16x8*)pk;
        }

        f32x4 acc[4];
        #pragma unroll
        for (int ot = 0; ot < 4; ++ot) acc[ot] = (f32x4){0.f, 0.f, 0.f, 0.f};

        if (wave < 2) {
            #pragma unroll
            for (int ks = 0; ks < 2; ++ks)
                #pragma unroll
                for (int ot = 0; ot < 4; ++ot)
                    acc[ot] = __builtin_amdgcn_mfma_f32_16x16x32_bf16(
                        wf[ot][ks], xf[ks], acc[ot], 0, 0, 0);
            ushort* dst = ((wave == 0) ? Q : K)
                        + ((size_t)bh * Tv + t0 + m) * Sv + quad * 4;
            #pragma unroll
            for (int ot = 0; ot < 4; ++ot) {
                uint2 w = {pkrn(acc[ot][0], acc[ot][1]), pkrn(acc[ot][2], acc[ot][3])};
                *(uint2*)(dst + ot * 16) = w;
            }
        } else {
            #pragma unroll
            for (int ks = 0; ks < 2; ++ks)
                #pragma unroll
                for (int st = 0; st < 4; ++st)
                    acc[st] = __builtin_amdgcn_mfma_f32_16x16x32_bf16(
                        xf[ks], wf[st][ks], acc[st], 0, 0, 0);
            ushort* vr = Vt + ((size_t)bh * Sv + m) * Tv + t0 + quad * 4;
            #pragma unroll
            for (int st = 0; st < 4; ++st) {
                uint2 w = {pkrn(acc[st][0], acc[st][1]), pkrn(acc[st][2], acc[st][3])};
                *(uint2*)(vr + (size_t)st * 16 * Tv) = w;
            }
        }
    }
}

// ---------------------------------------------------------------------------
// Kernel 2: flash attention v9 — round-0 structure (measured 87.5us; the
// depth-1 double-buffer of round 1 was -6%: vmcnt(0) drain not coverable
// by one compute phase, extra buffer addressing, LDS write/read contention)
// + T5 s_setprio around MFMA clusters. Mechanism: 4 independent blocks/CU
// at different phases; prio(1) during MFMA / prio(0) during exp2+pack lets
// the CU scheduler slot other waves' VALU under this wave's MFMA (m191:
// +4-7% on attn in exactly this regime; null only for lockstep GEMM).
// ---------------------------------------------------------------------------
__global__ __launch_bounds__(256, 4) void attn_kernel(
    const ushort* __restrict__ Q, const ushort* __restrict__ K,
    const ushort* __restrict__ Vt, ushort* __restrict__ O)
{
    __shared__ ushort kl[64 * 64];        // K tile  [key][d]   (swizzled)
    __shared__ ushort vl[64 * 64];        // Vt tile [s][key]   (swizzled)
    __shared__ float  ll[4][32];          // per-wave 1/lsum bounce

    const int tid  = threadIdx.x;
    const int wave = tid >> 6;
    const int lane = tid & 63;
    const int m    = lane & 15;
    const int quad = lane >> 4;
    const int bh   = blockIdx.x & 63;
    const int q0   = (blockIdx.x >> 6) << 7;   // query tile base (128)

    // Q fragments (B-operand of S^T = K·Q^T)
    const ushort* Qb = Q + ((size_t)bh * Tv + q0 + wave * 32) * Sv;
    bf16x8 qf[2][2];
    #pragma unroll
    for (int g = 0; g < 2; ++g)
        #pragma unroll
        for (int ks = 0; ks < 2; ++ks)
            qf[g][ks] = *(const bf16x8*)&Qb[(g * 16 + m) * Sv + ks * 32 + quad * 8];

    f32x4 oa[2][4];
    float lsum[2] = {0.f, 0.f};
    #pragma unroll
    for (int g = 0; g < 2; ++g)
        #pragma unroll
        for (int st = 0; st < 4; ++st)
            oa[g][st] = (f32x4){0.f, 0.f, 0.f, 0.f};

    const ushort* Kb = K  + (size_t)bh * Tv * Sv;
    const ushort* Vb = Vt + (size_t)bh * Sv * Tv;

    // staging geometry (swizzled): chunk c -> row=c>>3, phys cg=c&7,
    // source col-group = (c&7) ^ (row&7)
    const int r0 = tid >> 3,         cg0 = (tid & 7) ^ (r0 & 7);
    const int r1 = (256 + tid) >> 3, cg1 = ((256 + tid) & 7) ^ (r1 & 7);
    const size_t koff0 = (size_t)r0 * Sv + cg0 * 8;
    const size_t koff1 = (size_t)r1 * Sv + cg1 * 8;
    const size_t voff0 = (size_t)r0 * Tv + cg0 * 8;
    const size_t voff1 = (size_t)r1 * Tv + cg1 * 8;
    const int mx = m & 7;

    for (int k0 = 0; k0 < Tv; k0 += 64) {
        __syncthreads();
        async16(&kl[(size_t)tid * 8],         Kb + (size_t)k0 * Sv + koff0);
        async16(&kl[((size_t)tid + 256) * 8], Kb + (size_t)k0 * Sv + koff1);
        async16(&vl[(size_t)tid * 8],         Vb + k0 + voff0);
        async16(&vl[((size_t)tid + 256) * 8], Vb + k0 + voff1);
        __syncthreads();

        // S^T = K·Q^T -> exp2 -> P packed into registers (A-frag layout
        // of 16x16x16: lane (m,quad) = P[q=g*16+m][key=nt*16+quad*4+j])
        bf16x4 w[4][2];
        #pragma unroll
        for (int nt = 0; nt < 4; ++nt) {
            const int krow = nt * 16 + m;
            bf16x8 a0 = *(const bf16x8*)&kl[krow * 64 + ((quad       ^ mx) * 8)];
            bf16x8 a1 = *(const bf16x8*)&kl[krow * 64 + (((4 + quad) ^ mx) * 8)];
            #pragma unroll
            for (int g = 0; g < 2; ++g) {
                f32x4 s = (f32x4){0.f, 0.f, 0.f, 0.f};
                __builtin_amdgcn_s_setprio(1);
                s = __builtin_amdgcn_mfma_f32_16x16x32_bf16(a0, qf[g][0], s, 0, 0, 0);
                s = __builtin_amdgcn_mfma_f32_16x16x32_bf16(a1, qf[g][1], s, 0, 0, 0);
                __builtin_amdgcn_s_setprio(0);
                float p0 = __builtin_amdgcn_exp2f(s[0]);
                float p1 = __builtin_amdgcn_exp2f(s[1]);
                float p2 = __builtin_amdgcn_exp2f(s[2]);
                float p3 = __builtin_amdgcn_exp2f(s[3]);
                lsum[g] += (p0 + p1) + (p2 + p3);
                unsigned pk[2] = {pktr(p0, p1), pktr(p2, p3)};
                w[nt][g] = *(bf16x4*)pk;
            }
        }

        // PV via 16x16x16: A = w (registers), B = Vt b64 frags from vl.
        // B-frag (st,kt): Vt_tile[s=st*16+m][keys kt*16+quad*4 ..+3]
        #pragma unroll
        for (int st = 0; st < 4; ++st) {
            const int srow = st * 16 + m;
            bf16x4 vf[4];
            #pragma unroll
            for (int kt = 0; kt < 4; ++kt)
                vf[kt] = *(const bf16x4*)&vl[srow * 64
                           + (((2 * kt + (quad >> 1)) ^ mx) * 8) + (quad & 1) * 4];
            __builtin_amdgcn_s_setprio(1);
            #pragma unroll
            for (int g = 0; g < 2; ++g)
                #pragma unroll
                for (int kt = 0; kt < 4; ++kt)
                    oa[g][st] = MFMA161616(w[kt][g], vf[kt], oa[g][st]);
            __builtin_amdgcn_s_setprio(0);
        }
    }

    // lsum: reduce across quads; redistribute 1/l via wave-private LDS
    #pragma unroll
    for (int g = 0; g < 2; ++g) {
        lsum[g] += __shfl_xor(lsum[g], 16, 64);
        lsum[g] += __shfl_xor(lsum[g], 32, 64);
    }
    if (lane < 16) {
        ll[wave][lane]      = 1.0f / lsum[0];
        ll[wave][16 + lane] = 1.0f / lsum[1];
    }

    const int b = bh >> 4, h = bh & 15;
    #pragma unroll
    for (int g = 0; g < 2; ++g)
        #pragma unroll
        for (int st = 0; st < 4; ++st)
            #pragma unroll
            for (int r = 0; r < 4; ++r)
                O[((size_t)(b * Tv + q0 + wave * 32 + g * 16 + quad * 4 + r)) * Ev
                  + h * Sv + st * 16 + m]
                    = f2bf(oa[g][st][r] * ll[wave][g * 16 + quad * 4 + r]);
}

// ---------------------------------------------------------------------------
// Kernel 3: output projection, bf16 MFMA (m97 structure). Reverted to the
// round-0 single-buffer form (round-1 double-buffer was neutral; m190:
// setprio null on lockstep GEMM, so none here).
// ---------------------------------------------------------------------------
__global__ __launch_bounds__(256) void proj_kernel(
    const ushort* __restrict__ A, const ushort* __restrict__ B,
    const float* __restrict__ bp, float* __restrict__ C)
{
    __shared__ ushort Asm[128 * 32];
    __shared__ ushort Bsm[128 * 32];
    const int tid  = threadIdx.x;
    const int wave = tid >> 6;
    const int lane = tid & 63;
    const int m    = lane & 15;
    const int quad = lane >> 4;
    const int wm   = wave >> 1;
    const int wn   = wave & 1;
    const int m0   = blockIdx.x * 128;
    const int n0   = blockIdx.y * 128;

    f32x4 acc[4][4];
    #pragma unroll
    for (int i = 0; i < 4; ++i)
        #pragma unroll
        for (int j = 0; j < 4; ++j)
            acc[i][j] = (f32x4){0.f, 0.f, 0.f, 0.f};

    for (int k0 = 0; k0 < Ev; k0 += 32) {
        __syncthreads();
        #pragma unroll
        for (int j = 0; j < 2; ++j) {
            int c   = j * 256 + tid;
            int row = c >> 2;
            int col = (c & 3) * 8;
            async16(&Asm[c * 8], &A[(size_t)(m0 + row) * Ev + k0 + col]);
            async16(&Bsm[c * 8], &B[(size_t)(n0 + row) * Ev + k0 + col]);
        }
        __syncthreads();

        bf16x8 af[4], bf[4];
        #pragma unroll
        for (int i = 0; i < 4; ++i)
            af[i] = *(const bf16x8*)&Asm[(wm * 64 + i * 16 + m) * 32 + quad * 8];
        #pragma unroll
        for (int j = 0; j < 4; ++j)
            bf[j] = *(const bf16x8*)&Bsm[(wn * 64 + j * 16 + m) * 32 + quad * 8];
        #pragma unroll
        for (int i = 0; i < 4; ++i)
            #pragma unroll
            for (int j = 0; j < 4; ++j)
                acc[i][j] = __builtin_amdgcn_mfma_f32_16x16x32_bf16(
                    af[i], bf[j], acc[i][j], 0, 0, 0);
    }

    float bbv[4];
    #pragma unroll
    for (int j = 0; j < 4; ++j)
        bbv[j] = bp[n0 + wn * 64 + j * 16 + m];

    #pragma unroll
    for (int i = 0; i < 4; ++i)
        #pragma unroll
        for (int j = 0; j < 4; ++j)
            #pragma unroll
            for (int r = 0; r < 4; ++r)
                C[(size_t)(m0 + wm * 64 + i * 16 + quad * 4 + r) * Ev
                  + n0 + wn * 64 + j * 16 + m] = acc[i][j][r] + bbv[j];
}

// ---------------------------------------------------------------------------
// ws layout (ushort units):
//   Q 8.4M | K 8.4M | Vt 8.4M | O 8.4M | Wpb 1M | Wqb 4096 | Wkb 4096 | Wvb 4096
// ---------------------------------------------------------------------------
extern "C" void kernel_launch(void* const* d_in, const int* in_sizes, int n_in,
                              void* d_out, int out_size, void* d_ws, size_t ws_size,
                              hipStream_t stream) {
    const float* x  = (const float*)d_in[0];
    const float* Wk = (const float*)d_in[1];
    const float* Wq = (const float*)d_in[2];
    const float* Wv = (const float*)d_in[3];
    const float* Wp = (const float*)d_in[4];
    const float* bp = (const float*)d_in[5];
    float* out = (float*)d_out;

    ushort* Q   = (ushort*)d_ws;
    ushort* K   = Q   + 8388608;
    ushort* Vt  = K   + 8388608;
    ushort* O   = Vt  + 8388608;
    ushort* Wpb = O   + 8388608;
    ushort* Wqb = Wpb + 1048576;
    ushort* Wkb = Wqb + 4096;
    ushort* Wvb = Wkb + 4096;

    cast_kernel<<<1027, 256, 0, stream>>>(Wp, Wq, Wk, Wv, Wpb, Wqb, Wkb, Wvb);
    qkv_kernel<<<2048, 192, 0, stream>>>(x, Wqb, Wkb, Wvb, Q, K, Vt);
    attn_kernel<<<1024, 256, 0, stream>>>(Q, K, Vt, O);
    proj_kernel<<<dim3(64, 8), 256, 0, stream>>>(O, Wpb, bp, out);
}

// Round 3
// 222.163 us; speedup vs baseline: 1.0312x; 1.0127x over previous
//
#include <hip/hip_runtime.h>
#include <hip/hip_bf16.h>

#define Bv 4
#define Tv 2048
#define Ev 1024
#define Hv 16
#define Sv 64

typedef __attribute__((ext_vector_type(8))) short bf16x8;
typedef __attribute__((ext_vector_type(4))) short bf16x4;
typedef __attribute__((ext_vector_type(4))) float f32x4;
typedef __attribute__((ext_vector_type(16))) float f32x16;

__device__ __forceinline__ ushort f2bf(float f) {
    unsigned u = __float_as_uint(f);
    u = (u + 0x7FFFu + ((u >> 16) & 1u)) >> 16;
    return (ushort)u;
}
// RNE pack via v_cvt_pk_bf16_f32 (header lowers to HW instr on gfx950)
__device__ __forceinline__ unsigned pkrn(float a, float b) {
    __hip_bfloat162 t = __float22bfloat162_rn(make_float2(a, b));
    unsigned r; __builtin_memcpy(&r, &t, 4); return r;
}
// truncation pack, 1 VALU op (v_perm_b32): {lo=a_trunc, hi=b_trunc}
__device__ __forceinline__ unsigned pktr(float a, float b) {
    return __builtin_amdgcn_perm(__float_as_uint(b), __float_as_uint(a), 0x07060302u);
}

// async global->LDS, 16B per lane (global_load_lds_dwordx4)
__device__ __forceinline__ void async16(void* lds, const void* g) {
    __builtin_amdgcn_global_load_lds(
        (const __attribute__((address_space(1))) unsigned int*)g,
        (__attribute__((address_space(3))) unsigned int*)lds, 16, 0, 0);
}

// ---------------------------------------------------------------------------
// Kernel 0: cast weights fp32 -> bf16. Blocks 0..1023: Wp. 1024..1026: Wq/Wk/Wv
// Wq folded with (1/32)*log2(e): attn uses exp2 so v_exp_f32 needs no mul.
// ---------------------------------------------------------------------------
__global__ __launch_bounds__(256) void cast_kernel(
    const float* __restrict__ Wp, const float* __restrict__ Wq,
    const float* __restrict__ Wk, const float* __restrict__ Wv,
    ushort* __restrict__ Wpb, ushort* __restrict__ Wqb,
    ushort* __restrict__ Wkb, ushort* __restrict__ Wvb)
{
    int blk = blockIdx.x;
    if (blk < 1024) {
        int i = (blk * 256 + threadIdx.x) * 4;
        float4 v = *(const float4*)(Wp + i);
        uint2 o = {pkrn(v.x, v.y), pkrn(v.z, v.w)};
        *(uint2*)(Wpb + i) = o;
    } else {
        int p = blk - 1024;
        const float* src = (p == 0) ? Wq : ((p == 1) ? Wk : Wv);
        ushort* dst      = (p == 0) ? Wqb : ((p == 1) ? Wkb : Wvb);
        const float scale = (p == 0) ? 0.03125f * 1.4426950408889634f : 1.0f;
        #pragma unroll
        for (int it = 0; it < 4; ++it) {
            int i = (it * 256 + threadIdx.x) * 4;
            float4 v = *(const float4*)(src + i);
            uint2 o = {pkrn(v.x * scale, v.y * scale), pkrn(v.z * scale, v.w * scale)};
            *(uint2*)(dst + i) = o;
        }
    }
}

// ---------------------------------------------------------------------------
// Kernel 1: QKV projection via MFMA, no LDS. (unchanged)
// ---------------------------------------------------------------------------
__global__ __launch_bounds__(192) void qkv_kernel(
    const float* __restrict__ x,
    const ushort* __restrict__ Wqb, const ushort* __restrict__ Wkb,
    const ushort* __restrict__ Wvb,
    ushort* __restrict__ Q, ushort* __restrict__ K, ushort* __restrict__ Vt)
{
    const int tid  = threadIdx.x;
    const int wave = tid >> 6;        // 0=Q 1=K 2=V
    const int lane = tid & 63;
    const int m    = lane & 15;
    const int quad = lane >> 4;

    const ushort* Wsel = (wave == 0) ? Wqb : ((wave == 1) ? Wkb : Wvb);
    bf16x8 wf[4][2];
    #pragma unroll
    for (int ot = 0; ot < 4; ++ot)
        #pragma unroll
        for (int ks = 0; ks < 2; ++ks)
            wf[ot][ks] = *(const bf16x8*)&Wsel[(ot * 16 + m) * 64 + ks * 32 + quad * 8];

    const int tt = blockIdx.x >> 2;   // 0..511 token tile
    const int hg = blockIdx.x & 3;    // head group
    const int g0 = tt * 16;
    const int gm = g0 + m;
    const int b  = g0 >> 11;
    const int t0 = g0 & 2047;

    #pragma unroll
    for (int hi = 0; hi < 4; ++hi) {
        const int h  = hg * 4 + hi;
        const int bh = b * Hv + h;

        bf16x8 xf[2];
        #pragma unroll
        for (int ks = 0; ks < 2; ++ks) {
            const float* src = x + (size_t)gm * Ev + h * Sv + ks * 32 + quad * 8;
            float4 v0 = *(const float4*)src;
            float4 v1 = *(const float4*)(src + 4);
            unsigned pk[4];
            pk[0] = pkrn(v0.x, v0.y); pk[1] = pkrn(v0.z, v0.w);
            pk[2] = pkrn(v1.x, v1.y); pk[3] = pkrn(v1.z, v1.w);
            xf[ks] = *(bf16x8*)pk;
        }

        f32x4 acc[4];
        #pragma unroll
        for (int ot = 0; ot < 4; ++ot) acc[ot] = (f32x4){0.f, 0.f, 0.f, 0.f};

        if (wave < 2) {
            #pragma unroll
            for (int ks = 0; ks < 2; ++ks)
                #pragma unroll
                for (int ot = 0; ot < 4; ++ot)
                    acc[ot] = __builtin_amdgcn_mfma_f32_16x16x32_bf16(
                        wf[ot][ks], xf[ks], acc[ot], 0, 0, 0);
            ushort* dst = ((wave == 0) ? Q : K)
                        + ((size_t)bh * Tv + t0 + m) * Sv + quad * 4;
            #pragma unroll
            for (int ot = 0; ot < 4; ++ot) {
                uint2 w = {pkrn(acc[ot][0], acc[ot][1]), pkrn(acc[ot][2], acc[ot][3])};
                *(uint2*)(dst + ot * 16) = w;
            }
        } else {
            #pragma unroll
            for (int ks = 0; ks < 2; ++ks)
                #pragma unroll
                for (int st = 0; st < 4; ++st)
                    acc[st] = __builtin_amdgcn_mfma_f32_16x16x32_bf16(
                        xf[ks], wf[st][ks], acc[st], 0, 0, 0);
            ushort* vr = Vt + ((size_t)bh * Sv + m) * Tv + t0 + quad * 4;
            #pragma unroll
            for (int st = 0; st < 4; ++st) {
                uint2 w = {pkrn(acc[st][0], acc[st][1]), pkrn(acc[st][2], acc[st][3])};
                *(uint2*)(vr + (size_t)st * 16 * Tv) = w;
            }
        }
    }
}

// ---------------------------------------------------------------------------
// Kernel 2: flash attention v10 — 32x32x16 MFMA everywhere, FULL-RATE PV.
// v7/v9's PV used 16x16x16 (legacy half-rate shape): 32 MFMAs where 8
// full-rate ones suffice -> MFMA pipe ~930cy/block-iter, 57% of the 1640cy
// wall. New: QK^T = K·Q^T via 32x32x16 (lane q=l&31, hi=l>>5 holds S for
// keys (r&3)+4hi+8(r>>2)); exp2 -> pktr pairs -> TWO v_permlane32_swap_b32
// per 8 values rearrange P into the k=hi*8+j A-frag layout (T12) -> PV is
// 8x 32x32x16. Per wave-iter: 16 MFMA (was 48), 16 b128 DS (was 24), row
// sum is lane-local (1 lsum, one shfl at end). Staging/swizzle/barriers
// identical to the measured-best round-0 structure. No setprio (-8% r2).
// ---------------------------------------------------------------------------
__global__ __launch_bounds__(256, 4) void attn_kernel(
    const ushort* __restrict__ Q, const ushort* __restrict__ K,
    const ushort* __restrict__ Vt, ushort* __restrict__ O)
{
    __shared__ ushort kl[64 * 64];        // K tile  [key][d]   (swizzled)
    __shared__ ushort vl[64 * 64];        // Vt tile [s][key]   (swizzled)
    __shared__ float  ll[4][32];          // per-wave 1/lsum bounce

    const int tid  = threadIdx.x;
    const int wave = tid >> 6;
    const int lane = tid & 63;
    const int r31  = lane & 31;
    const int hi   = lane >> 5;
    const int bh   = blockIdx.x & 63;
    const int q0   = (blockIdx.x >> 6) << 7;   // query tile base (128)

    // Q B-frags (col = q = r31, k = ks*16 + hi*8 + j)
    const ushort* Qb = Q + ((size_t)bh * Tv + q0 + wave * 32 + r31) * Sv + hi * 8;
    bf16x8 qf[4];
    #pragma unroll
    for (int ks = 0; ks < 4; ++ks)
        qf[ks] = *(const bf16x8*)(Qb + ks * 16);

    f32x16 oa[2];
    #pragma unroll
    for (int st = 0; st < 2; ++st)
        #pragma unroll
        for (int r = 0; r < 16; ++r)
            oa[st][r] = 0.f;
    float lsum = 0.f;

    const ushort* Kb = K  + (size_t)bh * Tv * Sv;
    const ushort* Vb = Vt + (size_t)bh * Sv * Tv;

    // staging geometry (swizzled): chunk c -> row=c>>3, phys cg=c&7,
    // source col-group = (c&7) ^ (row&7)
    const int r0 = tid >> 3,         cg0 = (tid & 7) ^ (r0 & 7);
    const int r1 = (256 + tid) >> 3, cg1 = ((256 + tid) & 7) ^ (r1 & 7);
    const size_t koff0 = (size_t)r0 * Sv + cg0 * 8;
    const size_t koff1 = (size_t)r1 * Sv + cg1 * 8;
    const size_t voff0 = (size_t)r0 * Tv + cg0 * 8;
    const size_t voff1 = (size_t)r1 * Tv + cg1 * 8;
    const int swz = r31 & 7;

    for (int k0 = 0; k0 < Tv; k0 += 64) {
        __syncthreads();
        async16(&kl[(size_t)tid * 8],         Kb + (size_t)k0 * Sv + koff0);
        async16(&kl[((size_t)tid + 256) * 8], Kb + (size_t)k0 * Sv + koff1);
        async16(&vl[(size_t)tid * 8],         Vb + k0 + voff0);
        async16(&vl[((size_t)tid + 256) * 8], Vb + k0 + voff1);
        __syncthreads();

        #pragma unroll
        for (int kt = 0; kt < 2; ++kt) {
            // S^T = K·Q^T (32x32x16): D col = q = r31,
            // row = key_local = (r&3) + 4*hi + 8*(r>>2)
            f32x16 sacc;
            #pragma unroll
            for (int r = 0; r < 16; ++r) sacc[r] = 0.f;
            #pragma unroll
            for (int ks = 0; ks < 4; ++ks) {
                bf16x8 kf = *(const bf16x8*)
                    &kl[(kt * 32 + r31) * 64 + (((ks * 2 + hi) ^ swz) * 8)];
                sacc = __builtin_amdgcn_mfma_f32_32x32x16_bf16(
                    kf, qf[ks], sacc, 0, 0, 0);
            }

            // per 16-key half (kp): exp2 -> pack -> permlane32_swap into
            // full-rate A-frag (k = hi*8+j), then 2 PV MFMAs (s-tiles)
            #pragma unroll
            for (int kp = 0; kp < 2; ++kp) {
                float p[8];
                #pragma unroll
                for (int j = 0; j < 8; ++j)
                    p[j] = __builtin_amdgcn_exp2f(sacc[kp * 8 + j]);
                lsum += ((p[0] + p[1]) + (p[2] + p[3]))
                      + ((p[4] + p[5]) + (p[6] + p[7]));
                unsigned d0 = pktr(p[0], p[1]);
                unsigned d1 = pktr(p[2], p[3]);
                unsigned d2 = pktr(p[4], p[5]);
                unsigned d3 = pktr(p[6], p[7]);
                // d0' = {d0_lo, d2_lo} = w0 ; d2' = {d0_hi, d2_hi} = w2
                asm volatile("v_permlane32_swap_b32 %0, %1"
                             : "+v"(d0), "+v"(d2));
                asm volatile("v_permlane32_swap_b32 %0, %1"
                             : "+v"(d1), "+v"(d3));
                unsigned pw[4] = {d0, d1, d2, d3};
                bf16x8 pf = *(bf16x8*)pw;

                const int kc = (kt * 2 + kp) * 2 + hi;  // V col chunk
                #pragma unroll
                for (int st = 0; st < 2; ++st) {
                    bf16x8 vf = *(const bf16x8*)
                        &vl[(st * 32 + r31) * 64 + ((kc ^ swz) * 8)];
                    oa[st] = __builtin_amdgcn_mfma_f32_32x32x16_bf16(
                        pf, vf, oa[st], 0, 0, 0);
                }
            }
        }
    }

    // row sum: halves hold disjoint key sets for the same q -> one xor-32
    lsum += __shfl_xor(lsum, 32, 64);
    if (lane < 32) ll[wave][lane] = 1.0f / lsum;

    float sc[16];
    #pragma unroll
    for (int r = 0; r < 16; ++r)
        sc[r] = ll[wave][(r & 3) + 4 * hi + 8 * (r >> 2)];

    const int b = bh >> 4, h = bh & 15;
    #pragma unroll
    for (int st = 0; st < 2; ++st)
        #pragma unroll
        for (int r = 0; r < 16; ++r) {
            const int q = (r & 3) + 4 * hi + 8 * (r >> 2);
            O[((size_t)(b * Tv + q0 + wave * 32 + q)) * Ev
              + h * Sv + st * 32 + r31] = f2bf(oa[st][r] * sc[r]);
        }
}

// ---------------------------------------------------------------------------
// Kernel 3: output projection, bf16 MFMA (m97 structure, round-0 form).
// ---------------------------------------------------------------------------
__global__ __launch_bounds__(256) void proj_kernel(
    const ushort* __restrict__ A, const ushort* __restrict__ B,
    const float* __restrict__ bp, float* __restrict__ C)
{
    __shared__ ushort Asm[128 * 32];
    __shared__ ushort Bsm[128 * 32];
    const int tid  = threadIdx.x;
    const int wave = tid >> 6;
    const int lane = tid & 63;
    const int m    = lane & 15;
    const int quad = lane >> 4;
    const int wm   = wave >> 1;
    const int wn   = wave & 1;
    const int m0   = blockIdx.x * 128;
    const int n0   = blockIdx.y * 128;

    f32x4 acc[4][4];
    #pragma unroll
    for (int i = 0; i < 4; ++i)
        #pragma unroll
        for (int j = 0; j < 4; ++j)
            acc[i][j] = (f32x4){0.f, 0.f, 0.f, 0.f};

    for (int k0 = 0; k0 < Ev; k0 += 32) {
        __syncthreads();
        #pragma unroll
        for (int j = 0; j < 2; ++j) {
            int c   = j * 256 + tid;
            int row = c >> 2;
            int col = (c & 3) * 8;
            async16(&Asm[c * 8], &A[(size_t)(m0 + row) * Ev + k0 + col]);
            async16(&Bsm[c * 8], &B[(size_t)(n0 + row) * Ev + k0 + col]);
        }
        __syncthreads();

        bf16x8 af[4], bf[4];
        #pragma unroll
        for (int i = 0; i < 4; ++i)
            af[i] = *(const bf16x8*)&Asm[(wm * 64 + i * 16 + m) * 32 + quad * 8];
        #pragma unroll
        for (int j = 0; j < 4; ++j)
            bf[j] = *(const bf16x8*)&Bsm[(wn * 64 + j * 16 + m) * 32 + quad * 8];
        #pragma unroll
        for (int i = 0; i < 4; ++i)
            #pragma unroll
            for (int j = 0; j < 4; ++j)
                acc[i][j] = __builtin_amdgcn_mfma_f32_16x16x32_bf16(
                    af[i], bf[j], acc[i][j], 0, 0, 0);
    }

    float bbv[4];
    #pragma unroll
    for (int j = 0; j < 4; ++j)
        bbv[j] = bp[n0 + wn * 64 + j * 16 + m];

    #pragma unroll
    for (int i = 0; i < 4; ++i)
        #pragma unroll
        for (int j = 0; j < 4; ++j)
            #pragma unroll
            for (int r = 0; r < 4; ++r)
                C[(size_t)(m0 + wm * 64 + i * 16 + quad * 4 + r) * Ev
                  + n0 + wn * 64 + j * 16 + m] = acc[i][j][r] + bbv[j];
}

// ---------------------------------------------------------------------------
// ws layout (ushort units):
//   Q 8.4M | K 8.4M | Vt 8.4M | O 8.4M | Wpb 1M | Wqb 4096 | Wkb 4096 | Wvb 4096
// ---------------------------------------------------------------------------
extern "C" void kernel_launch(void* const* d_in, const int* in_sizes, int n_in,
                              void* d_out, int out_size, void* d_ws, size_t ws_size,
                              hipStream_t stream) {
    const float* x  = (const float*)d_in[0];
    const float* Wk = (const float*)d_in[1];
    const float* Wq = (const float*)d_in[2];
    const float* Wv = (const float*)d_in[3];
    const float* Wp = (const float*)d_in[4];
    const float* bp = (const float*)d_in[5];
    float* out = (float*)d_out;

    ushort* Q   = (ushort*)d_ws;
    ushort* K   = Q   + 8388608;
    ushort* Vt  = K   + 8388608;
    ushort* O   = Vt  + 8388608;
    ushort* Wpb = O   + 8388608;
    ushort* Wqb = Wpb + 1048576;
    ushort* Wkb = Wqb + 4096;
    ushort* Wvb = Wkb + 4096;

    cast_kernel<<<1027, 256, 0, stream>>>(Wp, Wq, Wk, Wv, Wpb, Wqb, Wkb, Wvb);
    qkv_kernel<<<2048, 192, 0, stream>>>(x, Wqb, Wkb, Wvb, Q, K, Vt);
    attn_kernel<<<1024, 256, 0, stream>>>(Q, K, Vt, O);
    proj_kernel<<<dim3(64, 8), 256, 0, stream>>>(O, Wpb, bp, out);
}